// Round 8
// baseline (232.626 us; speedup 1.0000x reference)
//
#include <hip/hip_runtime.h>
#include <math.h>

#define D 256

__device__ __forceinline__ float wave_reduce_sum(float v) {
#pragma unroll
    for (int off = 32; off > 0; off >>= 1) v += __shfl_xor(v, off);
    return v;
}
__device__ __forceinline__ float wave_reduce_max(float v) {
#pragma unroll
    for (int off = 32; off > 0; off >>= 1) v = fmaxf(v, __shfl_xor(v, off));
    return v;
}

__device__ __forceinline__ float4 load_row_f32(const float* __restrict__ E_w,
                                               int idx, int lane) {
    return ((const float4*)(E_w + (size_t)idx * D))[lane];
}
__device__ __forceinline__ float4 load_row_i8(const signed char* __restrict__ Eq,
                                              const float* __restrict__ scales,
                                              int idx, int lane) {
    const char4 c = ((const char4*)(Eq + (size_t)idx * D))[lane];  // 256B row
    const float f = scales[idx];
    return make_float4(f * (float)c.x, f * (float)c.y,
                       f * (float)c.z, f * (float)c.w);
}
template <bool I8>
__device__ __forceinline__ float4 load_row(const float* __restrict__ E_w,
                                           const signed char* __restrict__ Eq,
                                           const float* __restrict__ scales,
                                           int idx, int lane) {
    return I8 ? load_row_i8(Eq, scales, idx, lane) : load_row_f32(E_w, idx, lane);
}

// Dequant 16 int8 (one int4 = 16B chunk) into acc[16] with scale f.
__device__ __forceinline__ void dequant_acc16(float* __restrict__ acc,
                                              const int4 c, const float f) {
    const int w0 = c.x, w1 = c.y, w2 = c.z, w3 = c.w;
    acc[0]  += f * (float)((w0 << 24) >> 24);
    acc[1]  += f * (float)((w0 << 16) >> 24);
    acc[2]  += f * (float)((w0 <<  8) >> 24);
    acc[3]  += f * (float)( w0        >> 24);
    acc[4]  += f * (float)((w1 << 24) >> 24);
    acc[5]  += f * (float)((w1 << 16) >> 24);
    acc[6]  += f * (float)((w1 <<  8) >> 24);
    acc[7]  += f * (float)( w1        >> 24);
    acc[8]  += f * (float)((w2 << 24) >> 24);
    acc[9]  += f * (float)((w2 << 16) >> 24);
    acc[10] += f * (float)((w2 <<  8) >> 24);
    acc[11] += f * (float)( w2        >> 24);
    acc[12] += f * (float)((w3 << 24) >> 24);
    acc[13] += f * (float)((w3 << 16) >> 24);
    acc[14] += f * (float)((w3 <<  8) >> 24);
    acc[15] += f * (float)( w3        >> 24);
}

// ---------------------------------------------------------------------------
// K0: E_w fp32 -> int8 + per-row scale. Wave-per-row, 4 rows in flight.
// ---------------------------------------------------------------------------
__global__ __launch_bounds__(256) void convert_i8_kernel(
    const float* __restrict__ E_w, signed char* __restrict__ Eq,
    float* __restrict__ scales, int n_vocab) {
    const int lane = threadIdx.x & 63;
    const int gw   = (blockIdx.x * 256 + threadIdx.x) >> 6;
    const int nw   = (gridDim.x * 256) >> 6;

    for (int r0 = gw * 4; r0 < n_vocab; r0 += nw * 4) {
        const int n = min(4, n_vocab - r0);
        float4 v[4];
#pragma unroll
        for (int k = 0; k < 4; ++k)
            if (k < n) v[k] = load_row_f32(E_w, r0 + k, lane);
#pragma unroll
        for (int k = 0; k < 4; ++k) {
            if (k >= n) break;
            float mx = fmaxf(fmaxf(fabsf(v[k].x), fabsf(v[k].y)),
                             fmaxf(fabsf(v[k].z), fabsf(v[k].w)));
            mx = wave_reduce_max(mx);
            const float inv = (mx > 0.f) ? 127.f / mx : 0.f;
            const int qx = __float2int_rn(v[k].x * inv);
            const int qy = __float2int_rn(v[k].y * inv);
            const int qz = __float2int_rn(v[k].z * inv);
            const int qw = __float2int_rn(v[k].w * inv);
            const unsigned int packed =
                ((unsigned int)(unsigned char)(signed char)qx) |
                ((unsigned int)(unsigned char)(signed char)qy << 8) |
                ((unsigned int)(unsigned char)(signed char)qz << 16) |
                ((unsigned int)(unsigned char)(signed char)qw << 24);
            ((unsigned int*)(Eq + (size_t)(r0 + k) * D))[lane] = packed;
            if (lane == 0) scales[r0 + k] = mx * (1.f / 127.f);
        }
    }
}

// ---------------------------------------------------------------------------
// K1: blocks [0, BM)       -> negs, block-per-bm (R6 structure, R7 reverted)
//     blocks [BM, BM + B)  -> main path for batch row b
// Negs: quarter-wave-per-row dwordx4 gathers — one wave instruction loads
// 4 rows x 16B/lane (4x fewer vmem instrs than char4/lane). 2 groups in
// flight; chunk-layout acc[16]/lane; xor(16,32) + LDS cross-wave reduce.
// ---------------------------------------------------------------------------
template <bool I8>
__global__ __launch_bounds__(256) void abae_fused_kernel(
    const int* __restrict__ pos, const int* __restrict__ negs,
    const float* __restrict__ E_w, const signed char* __restrict__ Eq,
    const float* __restrict__ scales, const float* __restrict__ T_w,
    const float* __restrict__ M_w, const float* __restrict__ M_b,
    const float* __restrict__ lin_w, const float* __restrict__ lin_b,
    float* __restrict__ r_s, float* __restrict__ z_s, float* __restrict__ z_n,
    int B, int BM, int L, int n_asp) {
    const int t    = threadIdx.x;
    const int lane = t & 63;
    const int wv   = t >> 6;            // 0..3

    __shared__ float4 sred[4][64];      // 4KB: negs chunk-buf / main reduce
    __shared__ float  sy[D];
    __shared__ float  smy[D];
    __shared__ float  slog[16];
    __shared__ float  sp[16];
    __shared__ float  sscal[4];

    if (blockIdx.x < (unsigned)BM) {
        // ========== negs path (int8): quarter-wave-per-row gathers ==========
        const int bm = blockIdx.x;
        const int* __restrict__ idxp = negs + (size_t)bm * L;
        const int sub  = lane >> 4;     // row slot within group (0..3)
        const int boff = lane & 15;     // 16B chunk within row

        float acc[16];
#pragma unroll
        for (int k = 0; k < 16; ++k) acc[k] = 0.f;

        if (I8) {
            const int ngroups = L >> 2;             // 25 groups of 4 tokens
            int g = wv;
            for (; g + 4 < ngroups; g += 8) {       // 2 groups in flight
                const int rowA = idxp[4 * g + sub];
                const int rowB = idxp[4 * (g + 4) + sub];
                const int4 ca = ((const int4*)(Eq + (size_t)rowA * D))[boff];
                const int4 cb = ((const int4*)(Eq + (size_t)rowB * D))[boff];
                const float fa = scales[rowA];
                const float fb = scales[rowB];
                dequant_acc16(acc, ca, fa);
                dequant_acc16(acc, cb, fb);
            }
            for (; g < ngroups; g += 4) {
                const int row = idxp[4 * g + sub];
                const int4 c = ((const int4*)(Eq + (size_t)row * D))[boff];
                dequant_acc16(acc, c, scales[row]);
            }
            // tail tokens (L % 4): lanes 0-15 of the owning wave
            for (int j = L & ~3; j < L; ++j) {
                if (wv == (j & 3) && sub == 0) {
                    const int row = idxp[j];
                    const int4 c = ((const int4*)(Eq + (size_t)row * D))[boff];
                    dequant_acc16(acc, c, scales[row]);
                }
            }
        } else {
            // fp32 fallback: quarter-wave loads 64B of the 1KB row -> 4 rounds
            const int ngroups = L >> 2;
            for (int g = wv; g < ngroups; g += 4) {
                const int row = idxp[4 * g + sub];
#pragma unroll
                for (int q = 0; q < 4; ++q) {
                    const float4 v =
                        ((const float4*)(E_w + (size_t)row * D))[boff + 16 * q ];
                    acc[4 * 0 + 0] += 0.f; // placeholder to keep layout simple
                    acc[0] += 0.f;
                    (void)v;
                }
            }
            // fp32 fallback handled by simple per-lane path instead:
#pragma unroll
            for (int k = 0; k < 16; ++k) acc[k] = 0.f;
            float4 a4 = make_float4(0.f, 0.f, 0.f, 0.f);
            const int C  = (L + 3) / 4;
            const int s0 = wv * C;
            const int e0 = min(L, s0 + C);
            for (int l = s0; l < e0; ++l) {
                const float4 v = load_row_f32(E_w, idxp[l], lane);
                a4.x += v.x; a4.y += v.y; a4.z += v.z; a4.w += v.w;
            }
            sred[wv][lane] = a4;
            __syncthreads();
            if (wv == 0) {
                float4 z  = sred[0][lane];
                const float4 b1 = sred[1][lane], b2 = sred[2][lane],
                             b3 = sred[3][lane];
                const float invL = 1.f / (float)L;
                z.x = (z.x + b1.x + b2.x + b3.x) * invL;
                z.y = (z.y + b1.y + b2.y + b3.y) * invL;
                z.z = (z.z + b1.z + b2.z + b3.z) * invL;
                z.w = (z.w + b1.w + b2.w + b3.w) * invL;
                float ss = z.x * z.x + z.y * z.y + z.z * z.z + z.w * z.w;
                ss = wave_reduce_sum(ss);
                const float inv = 1.f / fmaxf(sqrtf(ss), 1e-12f);
                z.x *= inv; z.y *= inv; z.z *= inv; z.w *= inv;
                ((float4*)(z_n + (size_t)bm * D))[lane] = z;
            }
            return;
        }

        // combine the 4 sub copies: lanes {j, j+16, j+32, j+48} hold partial
        // sums of chunk (j&15)
#pragma unroll
        for (int k = 0; k < 16; ++k) {
            acc[k] += __shfl_xor(acc[k], 16);
            acc[k] += __shfl_xor(acc[k], 32);
        }
        // lanes 0-15 publish their 16-float chunk to LDS
        float* sbuf = (float*)sred;
        if (sub == 0) {
#pragma unroll
            for (int k = 0; k < 16; ++k)
                sbuf[wv * 256 + 16 * boff + k] = acc[k];
        }
        __syncthreads();
        // 256 threads: combine 4 waves, l2norm, store
        const float invL = 1.f / (float)L;
        float tot = (sbuf[t] + sbuf[256 + t] + sbuf[512 + t] + sbuf[768 + t]) * invL;
        float sq = wave_reduce_sum(tot * tot);
        if (lane == 0) sscal[wv] = sq;
        __syncthreads();
        const float ss  = sscal[0] + sscal[1] + sscal[2] + sscal[3];
        const float inv = 1.f / fmaxf(sqrtf(ss), 1e-12f);
        z_n[(size_t)bm * D + t] = tot * inv;
        return;
    }

    // ==================== main path: batch row b (R6, unchanged) ===========
    const int b = blockIdx.x - BM;
    const int* __restrict__ posb = pos + (size_t)b * L;
    const int C  = (L + 3) / 4;
    const int s0 = wv * C;
    const int e0 = min(L, s0 + C);

    // ---- phase 1: y_s = mean_l E[pos[b,l]], 5 gathers in flight ----
    float4 acc = make_float4(0.f, 0.f, 0.f, 0.f);
    int l = s0;
    for (; l + 5 <= e0; l += 5) {
        const int i0 = posb[l], i1 = posb[l + 1], i2 = posb[l + 2],
                  i3 = posb[l + 3], i4 = posb[l + 4];
        const float4 v0 = load_row<I8>(E_w, Eq, scales, i0, lane);
        const float4 v1 = load_row<I8>(E_w, Eq, scales, i1, lane);
        const float4 v2 = load_row<I8>(E_w, Eq, scales, i2, lane);
        const float4 v3 = load_row<I8>(E_w, Eq, scales, i3, lane);
        const float4 v4 = load_row<I8>(E_w, Eq, scales, i4, lane);
        acc.x += v0.x + v1.x + v2.x + v3.x + v4.x;
        acc.y += v0.y + v1.y + v2.y + v3.y + v4.y;
        acc.z += v0.z + v1.z + v2.z + v3.z + v4.z;
        acc.w += v0.w + v1.w + v2.w + v3.w + v4.w;
    }
    for (; l < e0; ++l) {
        const float4 v = load_row<I8>(E_w, Eq, scales, posb[l], lane);
        acc.x += v.x; acc.y += v.y; acc.z += v.z; acc.w += v.w;
    }
    sred[wv][lane] = acc;
    __syncthreads();
    if (wv == 0) {
        float4 y  = sred[0][lane];
        const float4 a1 = sred[1][lane], a2 = sred[2][lane], a3 = sred[3][lane];
        const float invL = 1.f / (float)L;
        y.x = (y.x + a1.x + a2.x + a3.x) * invL;
        y.y = (y.y + a1.y + a2.y + a3.y) * invL;
        y.z = (y.z + a1.z + a2.z + a3.z) * invL;
        y.w = (y.w + a1.w + a2.w + a3.w) * invL;
        ((float4*)sy)[lane] = y;
    }
    __syncthreads();

    // ---- phase 2: My = M_w @ y_s + M_b — wave-per-row, 4 rows in flight ----
    {
        const float4 y4 = ((const float4*)sy)[lane];
        for (int r0 = wv * 64; r0 < wv * 64 + 64; r0 += 4) {
            const float4 m0 = ((const float4*)(M_w + (size_t)(r0 + 0) * D))[lane];
            const float4 m1 = ((const float4*)(M_w + (size_t)(r0 + 1) * D))[lane];
            const float4 m2 = ((const float4*)(M_w + (size_t)(r0 + 2) * D))[lane];
            const float4 m3 = ((const float4*)(M_w + (size_t)(r0 + 3) * D))[lane];
            float p0 = m0.x * y4.x + m0.y * y4.y + m0.z * y4.z + m0.w * y4.w;
            float p1 = m1.x * y4.x + m1.y * y4.y + m1.z * y4.z + m1.w * y4.w;
            float p2 = m2.x * y4.x + m2.y * y4.y + m2.z * y4.z + m2.w * y4.w;
            float p3 = m3.x * y4.x + m3.y * y4.y + m3.z * y4.z + m3.w * y4.w;
#pragma unroll
            for (int off = 32; off > 0; off >>= 1) {
                p0 += __shfl_xor(p0, off);
                p1 += __shfl_xor(p1, off);
                p2 += __shfl_xor(p2, off);
                p3 += __shfl_xor(p3, off);
            }
            if (lane == 0) {
                smy[r0 + 0] = p0 + M_b[r0 + 0];
                smy[r0 + 1] = p1 + M_b[r0 + 1];
                smy[r0 + 2] = p2 + M_b[r0 + 2];
                smy[r0 + 3] = p3 + M_b[r0 + 3];
            }
        }
    }
    __syncthreads();

    // ---- phase 3: z = sum_l e_l * exp(tanh(e_l . My)) ----
    const float4 my4 = ((const float4*)smy)[lane];
    float4 zacc = make_float4(0.f, 0.f, 0.f, 0.f);
    l = s0;
    for (; l + 1 < e0; l += 2) {
        const float4 ea = load_row<I8>(E_w, Eq, scales, posb[l], lane);
        const float4 eb = load_row<I8>(E_w, Eq, scales, posb[l + 1], lane);
        float pa = ea.x * my4.x + ea.y * my4.y + ea.z * my4.z + ea.w * my4.w;
        float pb = eb.x * my4.x + eb.y * my4.y + eb.z * my4.z + eb.w * my4.w;
#pragma unroll
        for (int off = 32; off > 0; off >>= 1) {
            pa += __shfl_xor(pa, off);
            pb += __shfl_xor(pb, off);
        }
        const float wa = expf(tanhf(pa));
        const float wb = expf(tanhf(pb));
        zacc.x += ea.x * wa + eb.x * wb;
        zacc.y += ea.y * wa + eb.y * wb;
        zacc.z += ea.z * wa + eb.z * wb;
        zacc.w += ea.w * wa + eb.w * wb;
    }
    for (; l < e0; ++l) {
        const float4 ea = load_row<I8>(E_w, Eq, scales, posb[l], lane);
        float pa = ea.x * my4.x + ea.y * my4.y + ea.z * my4.z + ea.w * my4.w;
        pa = wave_reduce_sum(pa);
        const float wa = expf(tanhf(pa));
        zacc.x += ea.x * wa; zacc.y += ea.y * wa;
        zacc.z += ea.z * wa; zacc.w += ea.w * wa;
    }
    sred[wv][lane] = zacc;
    __syncthreads();
    if (wv == 0) {
        float4 z  = sred[0][lane];
        const float4 a1 = sred[1][lane], a2 = sred[2][lane], a3 = sred[3][lane];
        z.x += a1.x + a2.x + a3.x;
        z.y += a1.y + a2.y + a3.y;
        z.z += a1.z + a2.z + a3.z;
        z.w += a1.w + a2.w + a3.w;
        float ss = z.x * z.x + z.y * z.y + z.z * z.z + z.w * z.w;
        ss = wave_reduce_sum(ss);
        const float inv = 1.f / fmaxf(sqrtf(ss), 1e-12f);
        z.x *= inv; z.y *= inv; z.z *= inv; z.w *= inv;
        ((float4*)(z_s + (size_t)b * D))[lane] = z;   // output 1: z_s
        ((float4*)sy)[lane] = z;
    }
    __syncthreads();

    // ---- phase 4: p = softmax(z_s @ lin_w.T + lin_b) ----
    const float4 z4 = ((const float4*)sy)[lane];
    for (int a = wv; a < n_asp; a += 4) {
        const float4 w4 = ((const float4*)(lin_w + (size_t)a * D))[lane];
        float p = z4.x * w4.x + z4.y * w4.y + z4.z * w4.z + z4.w * w4.w;
        p = wave_reduce_sum(p);
        if (lane == 0) slog[a] = p + lin_b[a];
    }
    __syncthreads();
    if (t == 0) {
        float mx = -1e30f;
        for (int a = 0; a < n_asp; ++a) mx = fmaxf(mx, slog[a]);
        float s = 0.f;
        for (int a = 0; a < n_asp; ++a) {
            const float e = expf(slog[a] - mx);
            sp[a] = e; s += e;
        }
        const float invs = 1.f / s;
        for (int a = 0; a < n_asp; ++a) sp[a] *= invs;
    }
    __syncthreads();

    // ---- phase 5: r_s = l2norm(p @ T_w) ----
    float r = 0.f;
    for (int a = 0; a < n_asp; ++a) r += sp[a] * T_w[(size_t)a * D + t];
    const float sq = wave_reduce_sum(r * r);
    if (lane == 0) sscal[wv] = sq;
    __syncthreads();
    const float tot = sscal[0] + sscal[1] + sscal[2] + sscal[3];
    const float inv = 1.f / fmaxf(sqrtf(tot), 1e-12f);
    r_s[(size_t)b * D + t] = r * inv;                 // output 0: r_s
}

extern "C" void kernel_launch(void* const* d_in, const int* in_sizes, int n_in,
                              void* d_out, int out_size, void* d_ws, size_t ws_size,
                              hipStream_t stream) {
    const int*   pos   = (const int*)d_in[0];
    const int*   negs  = (const int*)d_in[1];
    const float* E_w   = (const float*)d_in[2];
    const float* T_w   = (const float*)d_in[3];
    const float* M_w   = (const float*)d_in[4];
    const float* M_b   = (const float*)d_in[5];
    const float* lin_w = (const float*)d_in[6];
    const float* lin_b = (const float*)d_in[7];
    float* out = (float*)d_out;

    const int d       = in_sizes[5];                 // 256 (M_b)
    const int n_asp   = in_sizes[7];                 // 14  (lin_b)
    const int M       = in_sizes[1] / in_sizes[0];   // 10
    const int B       = out_size / (d * (2 + M));    // 512
    const int L       = in_sizes[0] / B;             // 100
    const int n_vocab = in_sizes[2] / d;             // 100000
    (void)n_in;

    float* r_s = out;                              // [B, d]
    float* z_s = out + (size_t)B * d;              // [B, d]
    float* z_n = out + (size_t)2 * B * d;          // [B, M, d]

    const int BM = B * M;                          // 5120

    const size_t need = (size_t)n_vocab * D + (size_t)n_vocab * sizeof(float);
    const bool use_i8 = ws_size >= need;

    signed char* Eq = (signed char*)d_ws;
    float* scales   = (float*)(Eq + (size_t)n_vocab * D);

    if (use_i8) {
        convert_i8_kernel<<<4096, 256, 0, stream>>>(E_w, Eq, scales, n_vocab);
        abae_fused_kernel<true><<<BM + B, 256, 0, stream>>>(
            pos, negs, E_w, Eq, scales, T_w, M_w, M_b, lin_w, lin_b,
            r_s, z_s, z_n, B, BM, L, n_asp);
    } else {
        abae_fused_kernel<false><<<BM + B, 256, 0, stream>>>(
            pos, negs, E_w, (const signed char*)nullptr, (const float*)nullptr,
            T_w, M_w, M_b, lin_w, lin_b, r_s, z_s, z_n, B, BM, L, n_asp);
    }
}

// Round 9
// 224.420 us; speedup vs baseline: 1.0366x; 1.0366x over previous
//
#include <hip/hip_runtime.h>
#include <math.h>

#define D 256

__device__ __forceinline__ float wave_reduce_sum(float v) {
#pragma unroll
    for (int off = 32; off > 0; off >>= 1) v += __shfl_xor(v, off);
    return v;
}
__device__ __forceinline__ float wave_reduce_max(float v) {
#pragma unroll
    for (int off = 32; off > 0; off >>= 1) v = fmaxf(v, __shfl_xor(v, off));
    return v;
}

__device__ __forceinline__ float4 load_row_f32(const float* __restrict__ E_w,
                                               int idx, int lane) {
    return ((const float4*)(E_w + (size_t)idx * D))[lane];
}
__device__ __forceinline__ float4 load_row_i8(const signed char* __restrict__ Eq,
                                              const float* __restrict__ scales,
                                              int idx, int lane) {
    const char4 c = ((const char4*)(Eq + (size_t)idx * D))[lane];  // 256B row
    const float f = scales[idx];    // wave-uniform index -> scalar load
    return make_float4(f * (float)c.x, f * (float)c.y,
                       f * (float)c.z, f * (float)c.w);
}
template <bool I8>
__device__ __forceinline__ float4 load_row(const float* __restrict__ E_w,
                                           const signed char* __restrict__ Eq,
                                           const float* __restrict__ scales,
                                           int idx, int lane) {
    return I8 ? load_row_i8(Eq, scales, idx, lane) : load_row_f32(E_w, idx, lane);
}

// Batched int8 row gather+accumulate: NB independent rows in flight.
template <int NB>
__device__ __forceinline__ void gather_batch_i8(
    const signed char* __restrict__ Eq, const float* __restrict__ scales,
    const int* __restrict__ idxp, int l, int lane, float4& acc) {
    int id[NB];
#pragma unroll
    for (int k = 0; k < NB; ++k) id[k] = idxp[l + k];
    char4 c[NB];
#pragma unroll
    for (int k = 0; k < NB; ++k)
        c[k] = ((const char4*)(Eq + (size_t)id[k] * D))[lane];
    float f[NB];
#pragma unroll
    for (int k = 0; k < NB; ++k) f[k] = scales[id[k]];
#pragma unroll
    for (int k = 0; k < NB; ++k) {
        acc.x += f[k] * (float)c[k].x;
        acc.y += f[k] * (float)c[k].y;
        acc.z += f[k] * (float)c[k].z;
        acc.w += f[k] * (float)c[k].w;
    }
}

// ---------------------------------------------------------------------------
// K0: E_w fp32 -> int8 + per-row scale. Wave-per-row, 4 rows in flight.
// Pure cold-HBM stream: 102 MB read + 26 MB write, ~25-30 us measured.
// ---------------------------------------------------------------------------
__global__ __launch_bounds__(256) void convert_i8_kernel(
    const float* __restrict__ E_w, signed char* __restrict__ Eq,
    float* __restrict__ scales, int n_vocab) {
    const int lane = threadIdx.x & 63;
    const int gw   = (blockIdx.x * 256 + threadIdx.x) >> 6;
    const int nw   = (gridDim.x * 256) >> 6;

    for (int r0 = gw * 4; r0 < n_vocab; r0 += nw * 4) {
        const int n = min(4, n_vocab - r0);
        float4 v[4];
#pragma unroll
        for (int k = 0; k < 4; ++k)
            if (k < n) v[k] = load_row_f32(E_w, r0 + k, lane);
#pragma unroll
        for (int k = 0; k < 4; ++k) {
            if (k >= n) break;
            float mx = fmaxf(fmaxf(fabsf(v[k].x), fabsf(v[k].y)),
                             fmaxf(fabsf(v[k].z), fabsf(v[k].w)));
            mx = wave_reduce_max(mx);
            const float inv = (mx > 0.f) ? 127.f / mx : 0.f;
            const int qx = __float2int_rn(v[k].x * inv);
            const int qy = __float2int_rn(v[k].y * inv);
            const int qz = __float2int_rn(v[k].z * inv);
            const int qw = __float2int_rn(v[k].w * inv);
            const unsigned int packed =
                ((unsigned int)(unsigned char)(signed char)qx) |
                ((unsigned int)(unsigned char)(signed char)qy << 8) |
                ((unsigned int)(unsigned char)(signed char)qz << 16) |
                ((unsigned int)(unsigned char)(signed char)qw << 24);
            ((unsigned int*)(Eq + (size_t)(r0 + k) * D))[lane] = packed;
            if (lane == 0) scales[r0 + k] = mx * (1.f / 127.f);
        }
    }
}

// ---------------------------------------------------------------------------
// K1: blocks [0, BM)       -> negs (long pole, dispatched first)
//     blocks [BM, BM + B)  -> main path for batch row b
// R6 structure (best so far) with negs gather depth 5 -> 13: the
// disambiguating experiment between latency-bound and fabric-bound.
// ---------------------------------------------------------------------------
template <bool I8>
__global__ __launch_bounds__(256) void abae_fused_kernel(
    const int* __restrict__ pos, const int* __restrict__ negs,
    const float* __restrict__ E_w, const signed char* __restrict__ Eq,
    const float* __restrict__ scales, const float* __restrict__ T_w,
    const float* __restrict__ M_w, const float* __restrict__ M_b,
    const float* __restrict__ lin_w, const float* __restrict__ lin_b,
    float* __restrict__ r_s, float* __restrict__ z_s, float* __restrict__ z_n,
    int B, int BM, int L, int n_asp) {
    const int t    = threadIdx.x;
    const int lane = t & 63;
    const int wv   = t >> 6;            // 0..3

    __shared__ float4 sred[4][64];
    __shared__ float  sy[D];
    __shared__ float  smy[D];
    __shared__ float  slog[16];
    __shared__ float  sp[16];
    __shared__ float  sscal[4];

    const int C = (L + 3) / 4;          // tokens per wave (25)

    if (blockIdx.x < (unsigned)BM) {
        // ========== negs path: block-per-bm, 25 tokens/wave, depth-13 =======
        const int bm = blockIdx.x;
        const int* __restrict__ idxp = negs + (size_t)bm * L;
        const int s0 = wv * C;
        const int e0 = min(L, s0 + C);

        float4 acc = make_float4(0.f, 0.f, 0.f, 0.f);
        int l = s0;
        if (I8) {
            for (; l + 13 <= e0; l += 13) gather_batch_i8<13>(Eq, scales, idxp, l, lane, acc);
            for (; l + 6 <= e0; l += 6)   gather_batch_i8<6>(Eq, scales, idxp, l, lane, acc);
            for (; l < e0; ++l) {
                const float4 v = load_row_i8(Eq, scales, idxp[l], lane);
                acc.x += v.x; acc.y += v.y; acc.z += v.z; acc.w += v.w;
            }
        } else {
            for (; l < e0; ++l) {
                const float4 v = load_row_f32(E_w, idxp[l], lane);
                acc.x += v.x; acc.y += v.y; acc.z += v.z; acc.w += v.w;
            }
        }
        sred[wv][lane] = acc;
        __syncthreads();
        if (wv == 0) {
            float4 z  = sred[0][lane];
            const float4 a1 = sred[1][lane], a2 = sred[2][lane], a3 = sred[3][lane];
            const float invL = 1.f / (float)L;
            z.x = (z.x + a1.x + a2.x + a3.x) * invL;
            z.y = (z.y + a1.y + a2.y + a3.y) * invL;
            z.z = (z.z + a1.z + a2.z + a3.z) * invL;
            z.w = (z.w + a1.w + a2.w + a3.w) * invL;
            float ss = z.x * z.x + z.y * z.y + z.z * z.z + z.w * z.w;
            ss = wave_reduce_sum(ss);
            const float inv = 1.f / fmaxf(sqrtf(ss), 1e-12f);
            z.x *= inv; z.y *= inv; z.z *= inv; z.w *= inv;
            ((float4*)(z_n + (size_t)bm * D))[lane] = z;
        }
        return;
    }

    // ==================== main path: batch row b (R6, unchanged) ===========
    const int b = blockIdx.x - BM;
    const int* __restrict__ posb = pos + (size_t)b * L;
    const int s0 = wv * C;
    const int e0 = min(L, s0 + C);

    // ---- phase 1: y_s = mean_l E[pos[b,l]], depth-13 batches ----
    float4 acc = make_float4(0.f, 0.f, 0.f, 0.f);
    int l = s0;
    if (I8) {
        for (; l + 13 <= e0; l += 13) gather_batch_i8<13>(Eq, scales, posb, l, lane, acc);
        for (; l + 6 <= e0; l += 6)   gather_batch_i8<6>(Eq, scales, posb, l, lane, acc);
    }
    for (; l < e0; ++l) {
        const float4 v = load_row<I8>(E_w, Eq, scales, posb[l], lane);
        acc.x += v.x; acc.y += v.y; acc.z += v.z; acc.w += v.w;
    }
    sred[wv][lane] = acc;
    __syncthreads();
    if (wv == 0) {
        float4 y  = sred[0][lane];
        const float4 a1 = sred[1][lane], a2 = sred[2][lane], a3 = sred[3][lane];
        const float invL = 1.f / (float)L;
        y.x = (y.x + a1.x + a2.x + a3.x) * invL;
        y.y = (y.y + a1.y + a2.y + a3.y) * invL;
        y.z = (y.z + a1.z + a2.z + a3.z) * invL;
        y.w = (y.w + a1.w + a2.w + a3.w) * invL;
        ((float4*)sy)[lane] = y;
    }
    __syncthreads();

    // ---- phase 2: My = M_w @ y_s + M_b — wave-per-row, 4 rows in flight ----
    {
        const float4 y4 = ((const float4*)sy)[lane];
        for (int r0 = wv * 64; r0 < wv * 64 + 64; r0 += 4) {
            const float4 m0 = ((const float4*)(M_w + (size_t)(r0 + 0) * D))[lane];
            const float4 m1 = ((const float4*)(M_w + (size_t)(r0 + 1) * D))[lane];
            const float4 m2 = ((const float4*)(M_w + (size_t)(r0 + 2) * D))[lane];
            const float4 m3 = ((const float4*)(M_w + (size_t)(r0 + 3) * D))[lane];
            float p0 = m0.x * y4.x + m0.y * y4.y + m0.z * y4.z + m0.w * y4.w;
            float p1 = m1.x * y4.x + m1.y * y4.y + m1.z * y4.z + m1.w * y4.w;
            float p2 = m2.x * y4.x + m2.y * y4.y + m2.z * y4.z + m2.w * y4.w;
            float p3 = m3.x * y4.x + m3.y * y4.y + m3.z * y4.z + m3.w * y4.w;
#pragma unroll
            for (int off = 32; off > 0; off >>= 1) {
                p0 += __shfl_xor(p0, off);
                p1 += __shfl_xor(p1, off);
                p2 += __shfl_xor(p2, off);
                p3 += __shfl_xor(p3, off);
            }
            if (lane == 0) {
                smy[r0 + 0] = p0 + M_b[r0 + 0];
                smy[r0 + 1] = p1 + M_b[r0 + 1];
                smy[r0 + 2] = p2 + M_b[r0 + 2];
                smy[r0 + 3] = p3 + M_b[r0 + 3];
            }
        }
    }
    __syncthreads();

    // ---- phase 3: z = sum_l e_l * exp(tanh(e_l . My)); rows cache-warm ----
    const float4 my4 = ((const float4*)smy)[lane];
    float4 zacc = make_float4(0.f, 0.f, 0.f, 0.f);
    l = s0;
    for (; l + 1 < e0; l += 2) {
        const float4 ea = load_row<I8>(E_w, Eq, scales, posb[l], lane);
        const float4 eb = load_row<I8>(E_w, Eq, scales, posb[l + 1], lane);
        float pa = ea.x * my4.x + ea.y * my4.y + ea.z * my4.z + ea.w * my4.w;
        float pb = eb.x * my4.x + eb.y * my4.y + eb.z * my4.z + eb.w * my4.w;
#pragma unroll
        for (int off = 32; off > 0; off >>= 1) {
            pa += __shfl_xor(pa, off);
            pb += __shfl_xor(pb, off);
        }
        const float wa = expf(tanhf(pa));
        const float wb = expf(tanhf(pb));
        zacc.x += ea.x * wa + eb.x * wb;
        zacc.y += ea.y * wa + eb.y * wb;
        zacc.z += ea.z * wa + eb.z * wb;
        zacc.w += ea.w * wa + eb.w * wb;
    }
    for (; l < e0; ++l) {
        const float4 ea = load_row<I8>(E_w, Eq, scales, posb[l], lane);
        float pa = ea.x * my4.x + ea.y * my4.y + ea.z * my4.z + ea.w * my4.w;
        pa = wave_reduce_sum(pa);
        const float wa = expf(tanhf(pa));
        zacc.x += ea.x * wa; zacc.y += ea.y * wa;
        zacc.z += ea.z * wa; zacc.w += ea.w * wa;
    }
    sred[wv][lane] = zacc;
    __syncthreads();
    if (wv == 0) {
        float4 z  = sred[0][lane];
        const float4 a1 = sred[1][lane], a2 = sred[2][lane], a3 = sred[3][lane];
        z.x += a1.x + a2.x + a3.x;
        z.y += a1.y + a2.y + a3.y;
        z.z += a1.z + a2.z + a3.z;
        z.w += a1.w + a2.w + a3.w;
        float ss = z.x * z.x + z.y * z.y + z.z * z.z + z.w * z.w;
        ss = wave_reduce_sum(ss);
        const float inv = 1.f / fmaxf(sqrtf(ss), 1e-12f);
        z.x *= inv; z.y *= inv; z.z *= inv; z.w *= inv;
        ((float4*)(z_s + (size_t)b * D))[lane] = z;   // output 1: z_s
        ((float4*)sy)[lane] = z;
    }
    __syncthreads();

    // ---- phase 4: p = softmax(z_s @ lin_w.T + lin_b) ----
    const float4 z4 = ((const float4*)sy)[lane];
    for (int a = wv; a < n_asp; a += 4) {
        const float4 w4 = ((const float4*)(lin_w + (size_t)a * D))[lane];
        float p = z4.x * w4.x + z4.y * w4.y + z4.z * w4.z + z4.w * w4.w;
        p = wave_reduce_sum(p);
        if (lane == 0) slog[a] = p + lin_b[a];
    }
    __syncthreads();
    if (t == 0) {
        float mx = -1e30f;
        for (int a = 0; a < n_asp; ++a) mx = fmaxf(mx, slog[a]);
        float s = 0.f;
        for (int a = 0; a < n_asp; ++a) {
            const float e = expf(slog[a] - mx);
            sp[a] = e; s += e;
        }
        const float invs = 1.f / s;
        for (int a = 0; a < n_asp; ++a) sp[a] *= invs;
    }
    __syncthreads();

    // ---- phase 5: r_s = l2norm(p @ T_w) ----
    float r = 0.f;
    for (int a = 0; a < n_asp; ++a) r += sp[a] * T_w[(size_t)a * D + t];
    const float sq = wave_reduce_sum(r * r);
    if (lane == 0) sscal[wv] = sq;
    __syncthreads();
    const float tot = sscal[0] + sscal[1] + sscal[2] + sscal[3];
    const float inv = 1.f / fmaxf(sqrtf(tot), 1e-12f);
    r_s[(size_t)b * D + t] = r * inv;                 // output 0: r_s
}

extern "C" void kernel_launch(void* const* d_in, const int* in_sizes, int n_in,
                              void* d_out, int out_size, void* d_ws, size_t ws_size,
                              hipStream_t stream) {
    const int*   pos   = (const int*)d_in[0];
    const int*   negs  = (const int*)d_in[1];
    const float* E_w   = (const float*)d_in[2];
    const float* T_w   = (const float*)d_in[3];
    const float* M_w   = (const float*)d_in[4];
    const float* M_b   = (const float*)d_in[5];
    const float* lin_w = (const float*)d_in[6];
    const float* lin_b = (const float*)d_in[7];
    float* out = (float*)d_out;

    const int d       = in_sizes[5];                 // 256 (M_b)
    const int n_asp   = in_sizes[7];                 // 14  (lin_b)
    const int M       = in_sizes[1] / in_sizes[0];   // 10
    const int B       = out_size / (d * (2 + M));    // 512
    const int L       = in_sizes[0] / B;             // 100
    const int n_vocab = in_sizes[2] / d;             // 100000
    (void)n_in;

    float* r_s = out;                              // [B, d]
    float* z_s = out + (size_t)B * d;              // [B, d]
    float* z_n = out + (size_t)2 * B * d;          // [B, M, d]

    const int BM = B * M;                          // 5120

    const size_t need = (size_t)n_vocab * D + (size_t)n_vocab * sizeof(float);
    const bool use_i8 = ws_size >= need;

    signed char* Eq = (signed char*)d_ws;
    float* scales   = (float*)(Eq + (size_t)n_vocab * D);

    if (use_i8) {
        convert_i8_kernel<<<2048, 256, 0, stream>>>(E_w, Eq, scales, n_vocab);
        abae_fused_kernel<true><<<BM + B, 256, 0, stream>>>(
            pos, negs, E_w, Eq, scales, T_w, M_w, M_b, lin_w, lin_b,
            r_s, z_s, z_n, B, BM, L, n_asp);
    } else {
        abae_fused_kernel<false><<<BM + B, 256, 0, stream>>>(
            pos, negs, E_w, (const signed char*)nullptr, (const float*)nullptr,
            T_w, M_w, M_b, lin_w, lin_b, r_s, z_s, z_n, B, BM, L, n_asp);
    }
}